// Round 1
// baseline (560.924 us; speedup 1.0000x reference)
//
#include <hip/hip_runtime.h>
#include <hip/hip_bf16.h>
#include <math.h>

#define NUM_EMB 32
#define ADIM 32
#define HID 1024
#define BB 128
#define TT 64

typedef __attribute__((ext_vector_type(8))) __bf16 bf16x8;
typedef __attribute__((ext_vector_type(4))) float floatx4;

// ---------------- K0: counting-sort permutation by category ----------------
__global__ void perm_kernel(const int* __restrict__ cats, int* __restrict__ perm) {
  __shared__ int off[NUM_EMB];
  int tid = threadIdx.x;
  if (tid < NUM_EMB) off[tid] = 0;
  __syncthreads();
  if (tid < BB) atomicAdd(&off[cats[tid]], 1);
  __syncthreads();
  if (tid == 0) {
    int run = 0;
    for (int c = 0; c < NUM_EMB; ++c) { int v = off[c]; off[c] = run; run += v; }
  }
  __syncthreads();
  if (tid < BB) {
    int pos = atomicAdd(&off[cats[tid]], 1);
    perm[pos] = tid;
  }
}

// ---------------- K1: GEMM1 (fp32, K=32) + sinusoidal tau -> x2 bf16 -------
// x2 layout: [B, T, 2048] bf16, first 1024 = a_emb, second 1024 = tau.
// Block handles one b and 8 t-rows; 256 threads, 4 h-cols/thread.
__global__ __launch_bounds__(256) void embed_kernel(
    const float* __restrict__ actions, const float* __restrict__ timesteps,
    const float* __restrict__ W1w, const float* __restrict__ W1b,
    const int* __restrict__ cats, __bf16* __restrict__ x2) {
  const int b = blockIdx.y;
  const int t0 = blockIdx.x * 8;
  const int cat = cats[b];
  const int tid = threadIdx.x;

  __shared__ float act[8][ADIM];
  {
    int row = tid >> 5, k = tid & 31;
    act[row][k] = actions[((size_t)(b * TT + t0 + row)) * ADIM + k];
  }
  __syncthreads();

  const float* W = W1w + (size_t)cat * ADIM * HID;
  float acc[4][8];
#pragma unroll
  for (int ii = 0; ii < 4; ++ii) {
    float bv = W1b[cat * HID + tid + ii * 256];
#pragma unroll
    for (int tt = 0; tt < 8; ++tt) acc[ii][tt] = bv;
  }
  for (int k = 0; k < ADIM; ++k) {
#pragma unroll
    for (int ii = 0; ii < 4; ++ii) {
      float w = W[k * HID + tid + ii * 256];
#pragma unroll
      for (int tt = 0; tt < 8; ++tt) acc[ii][tt] += act[tt][k] * w;
    }
  }
#pragma unroll
  for (int ii = 0; ii < 4; ++ii) {
    int hcol = tid + ii * 256;
#pragma unroll
    for (int tt = 0; tt < 8; ++tt)
      x2[((size_t)(b * TT + t0 + tt)) * 2048 + hcol] = (__bf16)acc[ii][tt];
  }
  // tau (t-independent within b; recomputed once per 8 rows)
  float tb = timesteps[b];
  const float kLog = 9.210340371976184f;  // ln(10000)
#pragma unroll
  for (int ii = 0; ii < 4; ++ii) {
    int j = tid + ii * 256;
    int jj = (j < 512) ? j : (j - 512);
    float freq = tb * expf(-kLog * (float)jj * (1.0f / 512.0f));
    float v = (j < 512) ? sinf(freq) : cosf(freq);
    __bf16 hv = (__bf16)v;
#pragma unroll
    for (int tt = 0; tt < 8; ++tt)
      x2[((size_t)(b * TT + t0 + tt)) * 2048 + 1024 + j] = hv;
  }
}

// ---------------- K2/K3: grouped bf16 MFMA GEMM ----------------------------
// C[b] (64 x HID) = act( A[b] (64 x K) @ W[cat] (K x HID) + bias[cat] )
// Block tile: M=64, N=128, Kstep=32. 256 threads = 4 waves.
// Wave w: cols [w*32, w*32+32), all 64 rows -> 4 m-tiles x 2 n-tiles MFMA.
// LDS: As[64][40] bf16 (row-major m,k), Bs[128][40] bf16 (n-major, k contig).
// Stride 40 (80B) keeps b128 reads/writes bank-balanced.
template <bool SILU, bool OUT_BF16>
__global__ __launch_bounds__(256, 4) void gemm_kernel(
    const __bf16* __restrict__ A, const float* __restrict__ Wbase,
    const float* __restrict__ bias, const int* __restrict__ cats,
    const int* __restrict__ perm, void* __restrict__ Out, int K) {
  const int b = perm[blockIdx.y];
  const int cat = cats[b];
  const int nb = blockIdx.x * 128;
  const int tid = threadIdx.x;
  const int w = tid >> 6;
  const int lane = tid & 63;
  const int q = lane >> 4;
  const int r = lane & 15;

  __shared__ __attribute__((aligned(16))) __bf16 As[64 * 40];
  __shared__ __attribute__((aligned(16))) __bf16 Bs[128 * 40];

  const __bf16* Arow = A + (size_t)b * TT * K;
  const float* W = Wbase + (size_t)cat * K * HID;

  floatx4 acc[4][2];
#pragma unroll
  for (int mt = 0; mt < 4; ++mt)
#pragma unroll
    for (int nt = 0; nt < 2; ++nt) acc[mt][nt] = (floatx4){0.f, 0.f, 0.f, 0.f};

  const int am = tid >> 2;   // 0..63  (A row)
  const int ac = tid & 3;    // 0..3   (16B chunk within A row)
  const int bn = tid & 127;  // 0..127 (B col -> LDS row)
  const int bkb = tid >> 7;  // 0..1   (k-block; +2 for second task)

  for (int k0 = 0; k0 < K; k0 += 32) {
    // global loads first (overlap previous iteration's MFMA)
    uint4 av = *reinterpret_cast<const uint4*>(Arow + (size_t)am * K + k0 + ac * 8);
    float bvals[2][8];
#pragma unroll
    for (int i = 0; i < 2; ++i) {
      int kb = bkb + 2 * i;
      const float* Wp = W + (size_t)(k0 + kb * 8) * HID + nb + bn;
#pragma unroll
      for (int j = 0; j < 8; ++j) bvals[i][j] = Wp[(size_t)j * HID];
    }
    __syncthreads();  // previous iteration's frag reads done
    *reinterpret_cast<uint4*>(&As[am * 40 + ac * 8]) = av;
#pragma unroll
    for (int i = 0; i < 2; ++i) {
      int kb = bkb + 2 * i;
      union { uint4 u; __bf16 h[8]; } tmp;
#pragma unroll
      for (int j = 0; j < 8; ++j) tmp.h[j] = (__bf16)bvals[i][j];
      *reinterpret_cast<uint4*>(&Bs[bn * 40 + kb * 8]) = tmp.u;
    }
    __syncthreads();

    bf16x8 afrag[4], bfrag[2];
#pragma unroll
    for (int mt = 0; mt < 4; ++mt)
      afrag[mt] = *reinterpret_cast<const bf16x8*>(&As[(mt * 16 + r) * 40 + q * 8]);
#pragma unroll
    for (int nt = 0; nt < 2; ++nt)
      bfrag[nt] = *reinterpret_cast<const bf16x8*>(&Bs[(w * 32 + nt * 16 + r) * 40 + q * 8]);
#pragma unroll
    for (int mt = 0; mt < 4; ++mt)
#pragma unroll
      for (int nt = 0; nt < 2; ++nt)
        acc[mt][nt] = __builtin_amdgcn_mfma_f32_16x16x32_bf16(
            afrag[mt], bfrag[nt], acc[mt][nt], 0, 0, 0);
  }

  // epilogue: D row=(lane>>4)*4+reg, col=lane&15 (m89/m91-verified layout)
#pragma unroll
  for (int nt = 0; nt < 2; ++nt) {
    int col = nb + w * 32 + nt * 16 + r;
    float bv = bias[cat * HID + col];
#pragma unroll
    for (int mt = 0; mt < 4; ++mt) {
#pragma unroll
      for (int rr = 0; rr < 4; ++rr) {
        int m = mt * 16 + q * 4 + rr;
        float v = acc[mt][nt][rr] + bv;
        if (SILU) v = v / (1.0f + expf(-v));
        size_t oidx = ((size_t)(b * TT + m)) * HID + col;
        if (OUT_BF16)
          ((__bf16*)Out)[oidx] = (__bf16)v;
        else
          ((float*)Out)[oidx] = v;
      }
    }
  }
}

// ---------------- launcher -------------------------------------------------
extern "C" void kernel_launch(void* const* d_in, const int* in_sizes, int n_in,
                              void* d_out, int out_size, void* d_ws, size_t ws_size,
                              hipStream_t stream) {
  const float* actions = (const float*)d_in[0];
  const float* timesteps = (const float*)d_in[1];
  const float* W1w = (const float*)d_in[2];
  const float* W1b = (const float*)d_in[3];
  const float* W2w = (const float*)d_in[4];
  const float* W2b = (const float*)d_in[5];
  const float* W3w = (const float*)d_in[6];
  const float* W3b = (const float*)d_in[7];
  const int* cats = (const int*)d_in[8];
  float* out = (float*)d_out;

  char* ws = (char*)d_ws;
  __bf16* x2 = (__bf16*)ws;                              // 128*64*2048*2 = 33,554,432 B
  __bf16* h = (__bf16*)(ws + 33554432);                  // 128*64*1024*2 = 16,777,216 B
  int* perm = (int*)(ws + 33554432 + 16777216);          // 512 B

  perm_kernel<<<1, 128, 0, stream>>>(cats, perm);
  embed_kernel<<<dim3(8, BB), 256, 0, stream>>>(actions, timesteps, W1w, W1b, cats, x2);
  gemm_kernel<true, true><<<dim3(8, BB), 256, 0, stream>>>(x2, W2w, W2b, cats, perm, (void*)h, 2048);
  gemm_kernel<false, false><<<dim3(8, BB), 256, 0, stream>>>(h, W3w, W3b, cats, perm, (void*)out, 1024);
}